// Round 1
// baseline (264.653 us; speedup 1.0000x reference)
//
#include <hip/hip_runtime.h>
#include <hip/hip_bf16.h>

#define Bb 2
#define Ll 2048
#define Dd 768
#define HID 32
#define BL (Bb*Ll)   // 4096

typedef __hip_bfloat16 bf16;
typedef __attribute__((ext_vector_type(8))) short short8;     // 8 bf16 (4 VGPRs) per guide §3
typedef __attribute__((ext_vector_type(4))) float floatx4;

__device__ __forceinline__ float bf2f(bf16 x) { return __bfloat162float(x); }
__device__ __forceinline__ bf16  f2b(float x) { return __float2bfloat16(x); }

// ---------------- weight fp32 -> bf16 convert (4 matrices) ----------------
__global__ void convw_kernel(const float* __restrict__ wq, const float* __restrict__ wk,
                             const float* __restrict__ wv, const float* __restrict__ wo,
                             bf16* __restrict__ out) {
    int idx = blockIdx.x * 256 + threadIdx.x;        // float4 index
    const int per = Dd * Dd / 4;                     // 147456 float4 per matrix
    if (idx >= 4 * per) return;
    int w = idx / per, r = idx % per;
    const float* src = (w == 0) ? wq : (w == 1) ? wk : (w == 2) ? wv : wo;
    float4 v = reinterpret_cast<const float4*>(src)[r];
    bf16* o = out + (size_t)w * Dd * Dd + (size_t)r * 4;
    o[0] = f2b(v.x); o[1] = f2b(v.y); o[2] = f2b(v.z); o[3] = f2b(v.w);
}

// ---------------- gate MLP + h = hidden * gate ----------------
__global__ __launch_bounds__(256) void gate_kernel(
        const float* __restrict__ hidden, const float* __restrict__ sal,
        const float* __restrict__ gw1, const float* __restrict__ gb1,
        const float* __restrict__ gw2, const float* __restrict__ gb2,
        float* h_f, bf16* __restrict__ h_b) {
    int row = blockIdx.x;
    float s = sal[row];
    float h1[HID];
#pragma unroll
    for (int j = 0; j < HID; ++j) {
        float x = s * gw1[j] + gb1[j];
        h1[j] = x / (1.f + __expf(-x));              // silu
    }
    int t = threadIdx.x;
#pragma unroll
    for (int dl = 0; dl < 3; ++dl) {
        int d = t + dl * 256;
        const float4* g2 = reinterpret_cast<const float4*>(gw2 + (size_t)d * HID);
        float acc = gb2[d];
#pragma unroll
        for (int jj = 0; jj < 8; ++jj) {
            float4 w = g2[jj];
            acc += h1[4*jj+0]*w.x + h1[4*jj+1]*w.y + h1[4*jj+2]*w.z + h1[4*jj+3]*w.w;
        }
        float g = 1.f / (1.f + __expf(-acc));
        g = fminf(fmaxf(g, 0.05f), 0.95f);
        float hv = hidden[(size_t)row * Dd + d] * g;
        h_f[(size_t)row * Dd + d] = hv;
        h_b[(size_t)row * Dd + d] = f2b(hv);
    }
}

// ---------------- fused QKV GEMM: {q,k,v} = h @ w{q,k,v}^T + b, bf16 out ----------------
// grid = (18, 32): blockIdx.x = n-tile over [wq|wk|wv], blockIdx.y = m-tile.
// Block tile 128x128, 4 waves in 2x2, each wave 64x64 = 4x4 fragments of 16x16x32.
__global__ __launch_bounds__(256) void gemm_qkv(
        const bf16* __restrict__ A,
        const bf16* __restrict__ Wq, const bf16* __restrict__ Wk, const bf16* __restrict__ Wv,
        const float* __restrict__ bq, const float* __restrict__ bk, const float* __restrict__ bv,
        bf16* __restrict__ q, bf16* __restrict__ k, bf16* __restrict__ v) {
    int ntile = blockIdx.x, mtile = blockIdx.y;
    int tgt = ntile / 6;                  // 6 n-tiles of 128 per 768-wide matrix
    int n0 = (ntile % 6) * 128;
    const bf16* W = (tgt == 0) ? Wq : (tgt == 1) ? Wk : Wv;
    const float* bias = (tgt == 0) ? bq : (tgt == 1) ? bk : bv;
    bf16* out = (tgt == 0) ? q : (tgt == 1) ? k : v;
    int m0 = mtile * 128;

    int wave = threadIdx.x >> 6;
    int lane = threadIdx.x & 63;
    int wm = (wave >> 1) * 64;
    int wn = (wave & 1) * 64;
    int lrow = lane & 15;
    int koff = (lane >> 4) * 8;

    floatx4 acc[4][4] = {};
    const bf16* Abase = A + (size_t)(m0 + wm + lrow) * Dd + koff;
    const bf16* Wbase = W + (size_t)(n0 + wn + lrow) * Dd + koff;

    for (int k0 = 0; k0 < Dd; k0 += 32) {
        short8 a[4], b[4];
#pragma unroll
        for (int i = 0; i < 4; ++i)
            a[i] = *reinterpret_cast<const short8*>(Abase + (size_t)i * 16 * Dd + k0);
#pragma unroll
        for (int j = 0; j < 4; ++j)
            b[j] = *reinterpret_cast<const short8*>(Wbase + (size_t)j * 16 * Dd + k0);
#pragma unroll
        for (int i = 0; i < 4; ++i)
#pragma unroll
            for (int j = 0; j < 4; ++j)
                acc[i][j] = __builtin_amdgcn_mfma_f32_16x16x32_bf16(a[i], b[j], acc[i][j], 0, 0, 0);
    }

    int crow = (lane >> 4) * 4;
    int ccol = lane & 15;
#pragma unroll
    for (int i = 0; i < 4; ++i)
#pragma unroll
        for (int j = 0; j < 4; ++j) {
            int n = n0 + wn + j * 16 + ccol;
            float bb = bias[n];
#pragma unroll
            for (int r = 0; r < 4; ++r) {
                int m = m0 + wm + i * 16 + crow + r;
                out[(size_t)m * Dd + n] = f2b(acc[i][j][r] + bb);
            }
        }
}

// ---------------- output GEMM: out = merged @ wo^T + bo + h, fp32 out ----------------
__global__ __launch_bounds__(256) void gemm_out(
        const bf16* __restrict__ A, const bf16* __restrict__ W,
        const float* __restrict__ bias, const float* addend, float* out) {
    int n0 = blockIdx.x * 128;
    int m0 = blockIdx.y * 128;
    int wave = threadIdx.x >> 6;
    int lane = threadIdx.x & 63;
    int wm = (wave >> 1) * 64;
    int wn = (wave & 1) * 64;
    int lrow = lane & 15;
    int koff = (lane >> 4) * 8;

    floatx4 acc[4][4] = {};
    const bf16* Abase = A + (size_t)(m0 + wm + lrow) * Dd + koff;
    const bf16* Wbase = W + (size_t)(n0 + wn + lrow) * Dd + koff;

    for (int k0 = 0; k0 < Dd; k0 += 32) {
        short8 a[4], b[4];
#pragma unroll
        for (int i = 0; i < 4; ++i)
            a[i] = *reinterpret_cast<const short8*>(Abase + (size_t)i * 16 * Dd + k0);
#pragma unroll
        for (int j = 0; j < 4; ++j)
            b[j] = *reinterpret_cast<const short8*>(Wbase + (size_t)j * 16 * Dd + k0);
#pragma unroll
        for (int i = 0; i < 4; ++i)
#pragma unroll
            for (int j = 0; j < 4; ++j)
                acc[i][j] = __builtin_amdgcn_mfma_f32_16x16x32_bf16(a[i], b[j], acc[i][j], 0, 0, 0);
    }

    int crow = (lane >> 4) * 4;
    int ccol = lane & 15;
#pragma unroll
    for (int i = 0; i < 4; ++i)
#pragma unroll
        for (int j = 0; j < 4; ++j) {
            int n = n0 + wn + j * 16 + ccol;
            float bb = bias[n];
#pragma unroll
            for (int r = 0; r < 4; ++r) {
                int m = m0 + wm + i * 16 + crow + r;
                size_t o = (size_t)m * Dd + n;
                out[o] = acc[i][j][r] + bb + addend[o];
            }
        }
}

// ---------------- sliding-window attention (w=8 and w=32 fused) ----------------
// One block per (b,l). 32 scores (window-32 positions j -> key index l-31+j; last 8 are the w=8 window).
// Padding (key index < 0) scores against the raw bk vector and accumulates bv, exactly like the reference.
__global__ __launch_bounds__(256) void attn_kernel(
        const bf16* __restrict__ qb, const bf16* __restrict__ kb, const bf16* __restrict__ vb,
        const float* __restrict__ bkv, const float* __restrict__ bvv,
        bf16* __restrict__ merged) {
    __shared__ float sc[32];
    __shared__ float wgt[32];
    int l = blockIdx.x;
    int b = blockIdx.y;
    int row = b * Ll + l;
    int wave = threadIdx.x >> 6, lane = threadIdx.x & 63;

    float qr[12];
    const bf16* qrow = qb + (size_t)row * Dd;
#pragma unroll
    for (int t = 0; t < 12; ++t) qr[t] = bf2f(qrow[lane + t * 64]);

    const float scale = 0.03608439182435161f;  // 1/sqrt(768)
    for (int jj = wave * 8; jj < wave * 8 + 8; ++jj) {
        int kidx = l - 31 + jj;
        float p = 0.f;
        if (kidx >= 0) {
            const bf16* krow = kb + ((size_t)b * Ll + kidx) * Dd;
#pragma unroll
            for (int t = 0; t < 12; ++t) p += qr[t] * bf2f(krow[lane + t * 64]);
        } else {
#pragma unroll
            for (int t = 0; t < 12; ++t) p += qr[t] * bkv[lane + t * 64];
        }
#pragma unroll
        for (int off = 32; off; off >>= 1) p += __shfl_xor(p, off);
        if (lane == 0) sc[jj] = p * scale;
    }
    __syncthreads();

    if (threadIdx.x < 32) {
        int j = threadIdx.x;
        float m32 = -1e30f;
        for (int i = 0; i < 32; ++i) m32 = fmaxf(m32, sc[i]);
        float s32 = 0.f;
        for (int i = 0; i < 32; ++i) s32 += __expf(sc[i] - m32);
        float wv = __expf(sc[j] - m32) / s32;
        if (j >= 24) {   // w=8 window = last 8 positions
            float m8 = -1e30f;
            for (int i = 24; i < 32; ++i) m8 = fmaxf(m8, sc[i]);
            float s8 = 0.f;
            for (int i = 24; i < 32; ++i) s8 += __expf(sc[i] - m8);
            wv += __expf(sc[j] - m8) / s8;
        }
        wgt[j] = 0.5f * wv;
    }
    __syncthreads();

    int t = threadIdx.x;
    float a0 = 0.f, a1 = 0.f, a2 = 0.f;
    for (int jj = 0; jj < 32; ++jj) {
        float w = wgt[jj];
        int kidx = l - 31 + jj;
        if (kidx >= 0) {
            const bf16* vrow = vb + ((size_t)b * Ll + kidx) * Dd;
            a0 += w * bf2f(vrow[t]);
            a1 += w * bf2f(vrow[t + 256]);
            a2 += w * bf2f(vrow[t + 512]);
        } else {
            a0 += w * bvv[t];
            a1 += w * bvv[t + 256];
            a2 += w * bvv[t + 512];
        }
    }
    bf16* mrow = merged + (size_t)row * Dd;
    mrow[t]       = f2b(a0);
    mrow[t + 256] = f2b(a1);
    mrow[t + 512] = f2b(a2);
}

extern "C" void kernel_launch(void* const* d_in, const int* in_sizes, int n_in,
                              void* d_out, int out_size, void* d_ws, size_t ws_size,
                              hipStream_t stream) {
    const float* hidden = (const float*)d_in[0];
    const float* sal    = (const float*)d_in[1];
    const float* gw1    = (const float*)d_in[2];
    const float* gb1    = (const float*)d_in[3];
    const float* gw2    = (const float*)d_in[4];
    const float* gb2    = (const float*)d_in[5];
    const float* wq     = (const float*)d_in[6];
    const float* bq     = (const float*)d_in[7];
    const float* wk     = (const float*)d_in[8];
    const float* bk     = (const float*)d_in[9];
    const float* wv     = (const float*)d_in[10];
    const float* bv     = (const float*)d_in[11];
    const float* wo     = (const float*)d_in[12];
    const float* bo     = (const float*)d_in[13];
    float* out = (float*)d_out;

    const size_t nBL = (size_t)BL * Dd;
    char* p = (char*)d_ws;
    bf16* h_b = (bf16*)p; p += nBL * 2;
    bf16* q_b = (bf16*)p; p += nBL * 2;
    bf16* k_b = (bf16*)p; p += nBL * 2;
    bf16* v_b = (bf16*)p; p += nBL * 2;
    bf16* m_b = (bf16*)p; p += nBL * 2;
    bf16* w_b = (bf16*)p; p += (size_t)4 * Dd * Dd * 2;
    // residual h in fp32: use ws if it fits, else alias d_out (safe: gemm_out
    // reads addend[o] and writes out[o] elementwise, one thread per element).
    size_t used = (size_t)(p - (char*)d_ws);
    float* h_f;
    if (ws_size >= used + nBL * 4) { h_f = (float*)p; } else { h_f = out; }

    convw_kernel<<<dim3((4 * Dd * Dd / 4 + 255) / 256), 256, 0, stream>>>(wq, wk, wv, wo, w_b);
    gate_kernel<<<dim3(BL), 256, 0, stream>>>(hidden, sal, gw1, gb1, gw2, gb2, h_f, h_b);
    gemm_qkv<<<dim3(18, 32), 256, 0, stream>>>(h_b, w_b, w_b + (size_t)Dd * Dd, w_b + (size_t)2 * Dd * Dd,
                                               bq, bk, bv, q_b, k_b, v_b);
    attn_kernel<<<dim3(Ll, Bb), 256, 0, stream>>>(q_b, k_b, v_b, bk, bv, m_b);
    gemm_out<<<dim3(6, 32), 256, 0, stream>>>(m_b, w_b + (size_t)3 * Dd * Dd, bo, h_f, out);
}

// Round 2
// 190.131 us; speedup vs baseline: 1.3919x; 1.3919x over previous
//
#include <hip/hip_runtime.h>
#include <hip/hip_bf16.h>
#include <stdint.h>

#define Bb 2
#define Ll 2048
#define Dd 768
#define HID 32
#define BL (Bb*Ll)     // 4096
#define LP (Ll+31)     // padded K/V rows per batch

typedef __hip_bfloat16 bf16;
typedef __attribute__((ext_vector_type(8))) short short8;
typedef __attribute__((ext_vector_type(4))) float floatx4;

__device__ __forceinline__ float b2f(short u) {
    union { float f; unsigned i; } x; x.i = ((unsigned)(unsigned short)u) << 16; return x.f;
}
__device__ __forceinline__ bf16 f2b(float x) { return __float2bfloat16(x); }
__device__ __forceinline__ short f2bs(float x) {
    bf16 t = __float2bfloat16(x);
    union { bf16 h; short s; } u; u.h = t; return u.s;
}

typedef __attribute__((address_space(1))) const unsigned int guint;
typedef __attribute__((address_space(3))) unsigned int luint;
__device__ __forceinline__ void gload16(const bf16* g, bf16* l) {
    __builtin_amdgcn_global_load_lds((guint*)g, (luint*)l, 16, 0, 0);
}

// ---------------- weight fp32 -> bf16 convert (4 matrices) ----------------
__global__ void convw_kernel(const float* __restrict__ wq, const float* __restrict__ wk,
                             const float* __restrict__ wv, const float* __restrict__ wo,
                             bf16* __restrict__ out) {
    int idx = blockIdx.x * 256 + threadIdx.x;
    const int per = Dd * Dd / 4;
    if (idx >= 4 * per) return;
    int w = idx / per, r = idx % per;
    const float* src = (w == 0) ? wq : (w == 1) ? wk : (w == 2) ? wv : wo;
    float4 v = reinterpret_cast<const float4*>(src)[r];
    bf16* o = out + (size_t)w * Dd * Dd + (size_t)r * 4;
    o[0] = f2b(v.x); o[1] = f2b(v.y); o[2] = f2b(v.z); o[3] = f2b(v.w);
}

// ---------------- gate MLP + h = hidden * gate ----------------
__global__ __launch_bounds__(256) void gate_kernel(
        const float* __restrict__ hidden, const float* __restrict__ sal,
        const float* __restrict__ gw1, const float* __restrict__ gb1,
        const float* __restrict__ gw2, const float* __restrict__ gb2,
        float* __restrict__ h_f, bf16* __restrict__ h_b) {
    __shared__ float h1s[HID];
    int row = blockIdx.x;
    int t = threadIdx.x;
    if (t < HID) {
        float s = sal[row];
        float x = s * gw1[t] + gb1[t];
        h1s[t] = x / (1.f + __expf(-x));   // silu
    }
    __syncthreads();
#pragma unroll
    for (int dl = 0; dl < 3; ++dl) {
        int d = t + dl * 256;
        const float4* g2 = reinterpret_cast<const float4*>(gw2 + (size_t)d * HID);
        float acc = gb2[d];
#pragma unroll
        for (int jj = 0; jj < 8; ++jj) {
            float4 w = g2[jj];
            acc += h1s[4*jj+0]*w.x + h1s[4*jj+1]*w.y + h1s[4*jj+2]*w.z + h1s[4*jj+3]*w.w;
        }
        float g = 1.f / (1.f + __expf(-acc));
        g = fminf(fmaxf(g, 0.05f), 0.95f);
        float hv = hidden[(size_t)row * Dd + d] * g;
        h_f[(size_t)row * Dd + d] = hv;
        h_b[(size_t)row * Dd + d] = f2b(hv);
    }
}

// ---------------- pad fill: first 31 rows per batch of kp/vp = bias ----------------
__global__ void pad_kernel(const float* __restrict__ bk, const float* __restrict__ bv,
                           bf16* __restrict__ kp, bf16* __restrict__ vp) {
    int b = blockIdx.x / 31, row = blockIdx.x % 31;
    size_t base = ((size_t)b * LP + row) * Dd;
    for (int i = threadIdx.x; i < Dd; i += 256) {
        kp[base + i] = f2b(bk[i]);
        vp[base + i] = f2b(bv[i]);
    }
}

// ---------------- shared MFMA GEMM core: C = A(M x 768) * W(N x 768)^T ----------------
// m97 structure: 128 x (NF*32) tile, BK=64, global_load_lds width 16 with
// pre-swizzled global source (linear LDS dest), XOR-swizzled ds_read_b128.
template<int NF>   // wave n-frags: 4 -> BN=128, 2 -> BN=64
__device__ __forceinline__ void gemm_core(const bf16* __restrict__ Ag, const bf16* __restrict__ Wg,
                                          int m0, int n0, bf16* As, bf16* Bs,
                                          floatx4 (&acc)[4][NF]) {
    const int tid  = threadIdx.x;
    const int wave = tid >> 6, lane = tid & 63;
    const int lrow = lane & 15, koff = (lane >> 4) * 8;
    const int wm = (wave >> 1) * 64, wn = (wave & 1) * (NF * 16);
    const char* Asb = (const char*)As;
    const char* Bsb = (const char*)Bs;

    for (int k0 = 0; k0 < Dd; k0 += 64) {
        // stage A: 128x64 bf16 = 16KB, linear LDS, inverse-swizzled source
#pragma unroll
        for (int c = 0; c < 4; ++c) {
            int p = tid * 16 + c * 4096;              // linear LDS byte this lane fills
            int r = p >> 7;                           // row (128B rows)
            int o = (p & 127) ^ ((r & 7) << 4);       // swizzled source byte-in-row
            gload16(Ag + (size_t)(m0 + r) * Dd + k0 + (o >> 1),
                    As + (wave * 1024 + c * 4096) / 2);   // wave-uniform base
        }
        // stage B: NF*32 x 64 bf16
#pragma unroll
        for (int c = 0; c < NF; ++c) {
            int p = tid * 16 + c * 4096;
            int r = p >> 7;
            int o = (p & 127) ^ ((r & 7) << 4);
            gload16(Wg + (size_t)(n0 + r) * Dd + k0 + (o >> 1),
                    Bs + (wave * 1024 + c * 4096) / 2);
        }
        __syncthreads();   // includes vmcnt(0) drain of global_load_lds
#pragma unroll
        for (int kk = 0; kk < 64; kk += 32) {
            short8 a[4], b[NF];
#pragma unroll
            for (int i = 0; i < 4; ++i) {
                int row = wm + i * 16 + lrow;
                int byt = (row << 7) + (((kk + koff) * 2) ^ ((row & 7) << 4));
                a[i] = *reinterpret_cast<const short8*>(Asb + byt);
            }
#pragma unroll
            for (int j = 0; j < NF; ++j) {
                int row = wn + j * 16 + lrow;
                int byt = (row << 7) + (((kk + koff) * 2) ^ ((row & 7) << 4));
                b[j] = *reinterpret_cast<const short8*>(Bsb + byt);
            }
#pragma unroll
            for (int i = 0; i < 4; ++i)
#pragma unroll
                for (int j = 0; j < NF; ++j)
                    acc[i][j] = __builtin_amdgcn_mfma_f32_16x16x32_bf16(a[i], b[j], acc[i][j], 0, 0, 0);
        }
        __syncthreads();
    }
}

// ---------------- fused QKV GEMM, k/v written into padded arrays ----------------
__global__ __launch_bounds__(256) void gemm_qkv(
        const bf16* __restrict__ A, const bf16* __restrict__ W3,
        const float* __restrict__ bq, const float* __restrict__ bk, const float* __restrict__ bv,
        bf16* __restrict__ qo, bf16* __restrict__ kp, bf16* __restrict__ vp) {
    __shared__ bf16 As[128 * 64];
    __shared__ bf16 Bs[128 * 64];
    int ntile = blockIdx.x, mtile = blockIdx.y;
    int tgt = ntile / 6;
    int n0 = (ntile % 6) * 128;
    int m0 = mtile * 128;
    const bf16* W = W3 + (size_t)tgt * Dd * Dd;
    const float* bias = (tgt == 0) ? bq : (tgt == 1) ? bk : bv;
    bf16* out = (tgt == 0) ? qo : (tgt == 1) ? kp : vp;

    floatx4 acc[4][4] = {};
    gemm_core<4>(A, W, m0, n0, As, Bs, acc);

    int wave = threadIdx.x >> 6, lane = threadIdx.x & 63;
    int wm = (wave >> 1) * 64, wn = (wave & 1) * 64;
    int crow = (lane >> 4) * 4, ccol = lane & 15;
#pragma unroll
    for (int i = 0; i < 4; ++i)
#pragma unroll
        for (int j = 0; j < 4; ++j) {
            int n = n0 + wn + j * 16 + ccol;
            float bb = bias[n];
#pragma unroll
            for (int rr = 0; rr < 4; ++rr) {
                int m = m0 + wm + i * 16 + crow + rr;
                size_t orow = (tgt == 0) ? (size_t)m
                                         : ((size_t)(m >> 11) * LP + 31 + (m & 2047));
                out[orow * Dd + n] = f2b(acc[i][j][rr] + bb);
            }
        }
}

// ---------------- output GEMM: out = merged @ wo^T + bo + h (fp32) ----------------
__global__ __launch_bounds__(256) void gemm_out(
        const bf16* __restrict__ A, const bf16* __restrict__ W,
        const float* __restrict__ bias, const float* __restrict__ addend,
        float* __restrict__ out) {
    __shared__ bf16 As[128 * 64];
    __shared__ bf16 Bs[64 * 64];
    int n0 = blockIdx.x * 64, m0 = blockIdx.y * 128;

    floatx4 acc[4][2] = {};
    gemm_core<2>(A, W, m0, n0, As, Bs, acc);

    int wave = threadIdx.x >> 6, lane = threadIdx.x & 63;
    int wm = (wave >> 1) * 64, wn = (wave & 1) * 32;
    int crow = (lane >> 4) * 4, ccol = lane & 15;
#pragma unroll
    for (int i = 0; i < 4; ++i)
#pragma unroll
        for (int j = 0; j < 2; ++j) {
            int n = n0 + wn + j * 16 + ccol;
            float bb = bias[n];
#pragma unroll
            for (int rr = 0; rr < 4; ++rr) {
                int m = m0 + wm + i * 16 + crow + rr;
                size_t o = (size_t)m * Dd + n;
                out[o] = acc[i][j][rr] + bb + addend[o];
            }
        }
}

// ---------------- sliding-window attention: one wave per output row ----------------
// Padded K/V: key j for row l is padded row (l+j), j=0..31 — branch-free.
// In-register softmax (redundant across lanes), short8 vectorized loads/stores.
__global__ __launch_bounds__(256) void attn_kernel(
        const bf16* __restrict__ q, const bf16* __restrict__ kp, const bf16* __restrict__ vp,
        bf16* __restrict__ merged) {
    const int wave = threadIdx.x >> 6, lane = threadIdx.x & 63;
    const int r = blockIdx.x * 4 + wave;
    const int b = r >> 11, l = r & 2047;
    const size_t kvs = (size_t)LP * Dd;
    const bf16* kb = kp + (size_t)b * kvs + (size_t)l * Dd;
    const bf16* vb = vp + (size_t)b * kvs + (size_t)l * Dd;
    const bool half2 = lane < 32;
    const float scale = 0.03608439182435161f;   // 1/sqrt(768)

    // q: lane owns bf16 chunk [lane*8, +8); lanes<32 also own [512+lane*8, +8)
    const bf16* qrow = q + (size_t)r * Dd;
    float qa[8], qb2[8];
    {
        short8 t0 = *reinterpret_cast<const short8*>(qrow + lane * 8);
#pragma unroll
        for (int i = 0; i < 8; ++i) qa[i] = b2f(t0[i]);
        if (half2) {
            short8 t1 = *reinterpret_cast<const short8*>(qrow + 512 + lane * 8);
#pragma unroll
            for (int i = 0; i < 8; ++i) qb2[i] = b2f(t1[i]);
        }
    }

    float s[32];
#pragma unroll
    for (int j = 0; j < 32; ++j) {
        const bf16* kr = kb + (size_t)j * Dd;
        short8 ka = *reinterpret_cast<const short8*>(kr + lane * 8);
        float p = 0.f;
#pragma unroll
        for (int i = 0; i < 8; ++i) p += qa[i] * b2f(ka[i]);
        if (half2) {
            short8 kc = *reinterpret_cast<const short8*>(kr + 512 + lane * 8);
#pragma unroll
            for (int i = 0; i < 8; ++i) p += qb2[i] * b2f(kc[i]);
        }
#pragma unroll
        for (int off = 32; off; off >>= 1) p += __shfl_xor(p, off);
        s[j] = p * scale;
    }

    // softmax over 32 (w=32) and last 8 (w=8), computed in-register per lane
    float m32 = s[0];
#pragma unroll
    for (int j = 1; j < 32; ++j) m32 = fmaxf(m32, s[j]);
    float e[32], sum32 = 0.f;
#pragma unroll
    for (int j = 0; j < 32; ++j) { e[j] = __expf(s[j] - m32); sum32 += e[j]; }
    float m8 = s[24];
#pragma unroll
    for (int j = 25; j < 32; ++j) m8 = fmaxf(m8, s[j]);
    float e8[8], sum8 = 0.f;
#pragma unroll
    for (int j = 0; j < 8; ++j) { e8[j] = __expf(s[24 + j] - m8); sum8 += e8[j]; }
    float inv32 = 1.f / sum32, inv8 = 1.f / sum8;
    float w[32];
#pragma unroll
    for (int j = 0; j < 32; ++j) {
        float t = e[j] * inv32;
        if (j >= 24) t += e8[j - 24] * inv8;
        w[j] = 0.5f * t;
    }

    // PV
    float a0[8] = {}, a1[8] = {};
#pragma unroll
    for (int j = 0; j < 32; ++j) {
        const bf16* vr = vb + (size_t)j * Dd;
        short8 va = *reinterpret_cast<const short8*>(vr + lane * 8);
#pragma unroll
        for (int i = 0; i < 8; ++i) a0[i] += w[j] * b2f(va[i]);
        if (half2) {
            short8 vc = *reinterpret_cast<const short8*>(vr + 512 + lane * 8);
#pragma unroll
            for (int i = 0; i < 8; ++i) a1[i] += w[j] * b2f(vc[i]);
        }
    }

    bf16* mrow = merged + (size_t)r * Dd;
    short8 o0;
#pragma unroll
    for (int i = 0; i < 8; ++i) o0[i] = f2bs(a0[i]);
    *reinterpret_cast<short8*>(mrow + lane * 8) = o0;
    if (half2) {
        short8 o1;
#pragma unroll
        for (int i = 0; i < 8; ++i) o1[i] = f2bs(a1[i]);
        *reinterpret_cast<short8*>(mrow + 512 + lane * 8) = o1;
    }
}

extern "C" void kernel_launch(void* const* d_in, const int* in_sizes, int n_in,
                              void* d_out, int out_size, void* d_ws, size_t ws_size,
                              hipStream_t stream) {
    const float* hidden = (const float*)d_in[0];
    const float* sal    = (const float*)d_in[1];
    const float* gw1    = (const float*)d_in[2];
    const float* gb1    = (const float*)d_in[3];
    const float* gw2    = (const float*)d_in[4];
    const float* gb2    = (const float*)d_in[5];
    const float* wq     = (const float*)d_in[6];
    const float* bq     = (const float*)d_in[7];
    const float* wk     = (const float*)d_in[8];
    const float* bk     = (const float*)d_in[9];
    const float* wv     = (const float*)d_in[10];
    const float* bv     = (const float*)d_in[11];
    const float* wo     = (const float*)d_in[12];
    const float* bo     = (const float*)d_in[13];
    float* out = (float*)d_out;

    const size_t nBL  = (size_t)BL * Dd;
    const size_t nPad = (size_t)Bb * LP * Dd;
    char* p = (char*)d_ws;
    bf16* h_b = (bf16*)p; p += nBL * 2;
    bf16* q_b = (bf16*)p; p += nBL * 2;
    bf16* kpd = (bf16*)p; p += nPad * 2;
    bf16* vpd = (bf16*)p; p += nPad * 2;
    bf16* m_b = (bf16*)p; p += nBL * 2;
    bf16* w_b = (bf16*)p; p += (size_t)4 * Dd * Dd * 2;
    size_t used = (size_t)(p - (char*)d_ws);
    float* h_f = (ws_size >= used + nBL * 4) ? (float*)p : out;  // alias-safe in gemm_out

    convw_kernel<<<dim3((4 * Dd * Dd / 4 + 255) / 256), 256, 0, stream>>>(wq, wk, wv, wo, w_b);
    gate_kernel<<<dim3(BL), 256, 0, stream>>>(hidden, sal, gw1, gb1, gw2, gb2, h_f, h_b);
    pad_kernel<<<dim3(Bb * 31), 256, 0, stream>>>(bk, bv, kpd, vpd);
    gemm_qkv<<<dim3(18, 32), 256, 0, stream>>>(h_b, w_b, bq, bk, bv, q_b, kpd, vpd);
    attn_kernel<<<dim3(BL / 4), 256, 0, stream>>>(q_b, kpd, vpd, m_b);
    gemm_out<<<dim3(12, 32), 256, 0, stream>>>(m_b, w_b + (size_t)3 * Dd * Dd, bo, h_f, out);
}

// Round 3
// 140.372 us; speedup vs baseline: 1.8854x; 1.3545x over previous
//
#include <hip/hip_runtime.h>
#include <hip/hip_bf16.h>
#include <stdint.h>

#define Bb 2
#define Ll 2048
#define Dd 768
#define HID 32
#define BL (Bb*Ll)     // 4096
#define LP (Ll+31)     // padded K/V rows per batch

typedef __hip_bfloat16 bf16;
typedef __attribute__((ext_vector_type(8))) short short8;
typedef __attribute__((ext_vector_type(4))) short short4s;
typedef __attribute__((ext_vector_type(4))) float floatx4;

__device__ __forceinline__ float b2f(short u) {
    union { float f; unsigned i; } x; x.i = ((unsigned)(unsigned short)u) << 16; return x.f;
}
__device__ __forceinline__ bf16 f2b(float x) { return __float2bfloat16(x); }
__device__ __forceinline__ short f2bs(float x) {
    bf16 t = __float2bfloat16(x);
    union { bf16 h; short s; } u; u.h = t; return u.s;
}

typedef __attribute__((address_space(1))) const unsigned int guint;
typedef __attribute__((address_space(3))) unsigned int luint;
__device__ __forceinline__ void gload16(const bf16* g, bf16* l) {
    __builtin_amdgcn_global_load_lds((guint*)g, (luint*)l, 16, 0, 0);
}

// ---------------- weight convert + K/V pad fill (fused) ----------------
#define CONV_BLOCKS 2304   // 4*768*768/4 float4 / 256
__global__ void prep_kernel(const float* __restrict__ wq, const float* __restrict__ wk,
                            const float* __restrict__ wv, const float* __restrict__ wo,
                            const float* __restrict__ bk, const float* __restrict__ bv,
                            bf16* __restrict__ wout, bf16* __restrict__ kp, bf16* __restrict__ vp) {
    if (blockIdx.x < CONV_BLOCKS) {
        int idx = blockIdx.x * 256 + threadIdx.x;
        const int per = Dd * Dd / 4;
        int w = idx / per, r = idx % per;
        const float* src = (w == 0) ? wq : (w == 1) ? wk : (w == 2) ? wv : wo;
        float4 v = reinterpret_cast<const float4*>(src)[r];
        bf16* o = wout + (size_t)w * Dd * Dd + (size_t)r * 4;
        o[0] = f2b(v.x); o[1] = f2b(v.y); o[2] = f2b(v.z); o[3] = f2b(v.w);
    } else {
        int pb = blockIdx.x - CONV_BLOCKS;        // 0..61
        int b = pb / 31, row = pb % 31;
        size_t base = ((size_t)b * LP + row) * Dd;
        for (int i = threadIdx.x; i < Dd; i += 256) {
            kp[base + i] = f2b(bk[i]);
            vp[base + i] = f2b(bv[i]);
        }
    }
}

// ---------------- gate MLP + h = hidden * gate ----------------
__global__ __launch_bounds__(256) void gate_kernel(
        const float* __restrict__ hidden, const float* __restrict__ sal,
        const float* __restrict__ gw1, const float* __restrict__ gb1,
        const float* __restrict__ gw2, const float* __restrict__ gb2,
        float* __restrict__ h_f, bf16* __restrict__ h_b) {
    __shared__ float h1s[HID];
    int row = blockIdx.x;
    int t = threadIdx.x;
    if (t < HID) {
        float s = sal[row];
        float x = s * gw1[t] + gb1[t];
        h1s[t] = x / (1.f + __expf(-x));   // silu
    }
    __syncthreads();
#pragma unroll
    for (int dl = 0; dl < 3; ++dl) {
        int d = t + dl * 256;
        const float4* g2 = reinterpret_cast<const float4*>(gw2 + (size_t)d * HID);
        float acc = gb2[d];
#pragma unroll
        for (int jj = 0; jj < 8; ++jj) {
            float4 w = g2[jj];
            acc += h1s[4*jj+0]*w.x + h1s[4*jj+1]*w.y + h1s[4*jj+2]*w.z + h1s[4*jj+3]*w.w;
        }
        float g = 1.f / (1.f + __expf(-acc));
        g = fminf(fmaxf(g, 0.05f), 0.95f);
        float hv = hidden[(size_t)row * Dd + d] * g;
        h_f[(size_t)row * Dd + d] = hv;
        h_b[(size_t)row * Dd + d] = f2b(hv);
    }
}

// ---------------- shared MFMA GEMM core: C = A(M x 768) * W(N x 768)^T ----------------
// m97 structure: 128 x (NF*32) tile, BK=64, global_load_lds width 16 with
// pre-swizzled global source (linear LDS dest), XOR-swizzled ds_read_b128.
template<int NF>   // wave n-frags: 4 -> BN=128, 2 -> BN=64
__device__ __forceinline__ void gemm_core(const bf16* __restrict__ Ag, const bf16* __restrict__ Wg,
                                          int m0, int n0, bf16* As, bf16* Bs,
                                          floatx4 (&acc)[4][NF]) {
    const int tid  = threadIdx.x;
    const int wave = tid >> 6, lane = tid & 63;
    const int lrow = lane & 15, koff = (lane >> 4) * 8;
    const int wm = (wave >> 1) * 64, wn = (wave & 1) * (NF * 16);
    const char* Asb = (const char*)As;
    const char* Bsb = (const char*)Bs;

    for (int k0 = 0; k0 < Dd; k0 += 64) {
        // stage A: 128x64 bf16 = 16KB, linear LDS, inverse-swizzled source
#pragma unroll
        for (int c = 0; c < 4; ++c) {
            int p = tid * 16 + c * 4096;              // linear LDS byte this lane fills
            int r = p >> 7;                           // row (128B rows)
            int o = (p & 127) ^ ((r & 7) << 4);       // swizzled source byte-in-row
            gload16(Ag + (size_t)(m0 + r) * Dd + k0 + (o >> 1),
                    As + (wave * 1024 + c * 4096) / 2);   // wave-uniform base
        }
        // stage B: NF*32 x 64 bf16
#pragma unroll
        for (int c = 0; c < NF; ++c) {
            int p = tid * 16 + c * 4096;
            int r = p >> 7;
            int o = (p & 127) ^ ((r & 7) << 4);
            gload16(Wg + (size_t)(n0 + r) * Dd + k0 + (o >> 1),
                    Bs + (wave * 1024 + c * 4096) / 2);
        }
        __syncthreads();   // includes vmcnt(0) drain of global_load_lds
#pragma unroll
        for (int kk = 0; kk < 64; kk += 32) {
            short8 a[4], b[NF];
#pragma unroll
            for (int i = 0; i < 4; ++i) {
                int row = wm + i * 16 + lrow;
                int byt = (row << 7) + (((kk + koff) * 2) ^ ((row & 7) << 4));
                a[i] = *reinterpret_cast<const short8*>(Asb + byt);
            }
#pragma unroll
            for (int j = 0; j < NF; ++j) {
                int row = wn + j * 16 + lrow;
                int byt = (row << 7) + (((kk + koff) * 2) ^ ((row & 7) << 4));
                b[j] = *reinterpret_cast<const short8*>(Bsb + byt);
            }
#pragma unroll
            for (int i = 0; i < 4; ++i)
#pragma unroll
                for (int j = 0; j < NF; ++j)
                    acc[i][j] = __builtin_amdgcn_mfma_f32_16x16x32_bf16(a[i], b[j], acc[i][j], 0, 0, 0);
        }
        __syncthreads();
    }
}

// ---------------- fused QKV GEMM, k/v written into padded arrays ----------------
// 1D grid 576, XCD-chunked 2D swizzle: 8 XCDs as 4(m) x 2(n) chunks of 8 mtiles x 9 ntiles.
__global__ __launch_bounds__(256) void gemm_qkv(
        const bf16* __restrict__ A, const bf16* __restrict__ W3,
        const float* __restrict__ bq, const float* __restrict__ bk, const float* __restrict__ bv,
        bf16* __restrict__ qo, bf16* __restrict__ kp, bf16* __restrict__ vp) {
    __shared__ bf16 As[128 * 64];
    __shared__ bf16 Bs[128 * 64];
    int bid = blockIdx.x;
    int xcd = bid & 7, idx = bid >> 3;       // idx in [0,72)
    int mtile = (xcd >> 1) * 8 + (idx & 7);  // [0,32)
    int ntile = (xcd & 1) * 9 + (idx >> 3);  // [0,18)
    int tgt = ntile / 6;
    int n0 = (ntile % 6) * 128;
    int m0 = mtile * 128;
    const bf16* W = W3 + (size_t)tgt * Dd * Dd;
    const float* bias = (tgt == 0) ? bq : (tgt == 1) ? bk : bv;
    bf16* out = (tgt == 0) ? qo : (tgt == 1) ? kp : vp;

    floatx4 acc[4][4] = {};
    gemm_core<4>(A, W, m0, n0, As, Bs, acc);

    int wave = threadIdx.x >> 6, lane = threadIdx.x & 63;
    int wm = (wave >> 1) * 64, wn = (wave & 1) * 64;
    int crow = (lane >> 4) * 4, ccol = lane & 15;
#pragma unroll
    for (int i = 0; i < 4; ++i)
#pragma unroll
        for (int j = 0; j < 4; ++j) {
            int n = n0 + wn + j * 16 + ccol;
            float bb = bias[n];
#pragma unroll
            for (int rr = 0; rr < 4; ++rr) {
                int m = m0 + wm + i * 16 + crow + rr;
                size_t orow = (tgt == 0) ? (size_t)m
                                         : ((size_t)(m >> 11) * LP + 31 + (m & 2047));
                out[orow * Dd + n] = f2b(acc[i][j][rr] + bb);
            }
        }
}

// ---------------- output GEMM: out = merged @ wo^T + bo + h (fp32) ----------------
// 1D grid 384, XCD-chunked: 4(m) x 2(n) chunks of 8 mtiles x 6 ntiles.
__global__ __launch_bounds__(256) void gemm_out(
        const bf16* __restrict__ A, const bf16* __restrict__ W,
        const float* __restrict__ bias, const float* __restrict__ addend,
        float* __restrict__ out) {
    __shared__ bf16 As[128 * 64];
    __shared__ bf16 Bs[64 * 64];
    int bid = blockIdx.x;
    int xcd = bid & 7, idx = bid >> 3;       // idx in [0,48)
    int mtile = (xcd >> 1) * 8 + (idx & 7);  // [0,32)
    int ntile = (xcd & 1) * 6 + (idx >> 3);  // [0,12)
    int n0 = ntile * 64, m0 = mtile * 128;

    floatx4 acc[4][2] = {};
    gemm_core<2>(A, W, m0, n0, As, Bs, acc);

    int wave = threadIdx.x >> 6, lane = threadIdx.x & 63;
    int wm = (wave >> 1) * 64, wn = (wave & 1) * 32;
    int crow = (lane >> 4) * 4, ccol = lane & 15;
#pragma unroll
    for (int i = 0; i < 4; ++i)
#pragma unroll
        for (int j = 0; j < 2; ++j) {
            int n = n0 + wn + j * 16 + ccol;
            float bb = bias[n];
#pragma unroll
            for (int rr = 0; rr < 4; ++rr) {
                int m = m0 + wm + i * 16 + crow + rr;
                size_t o = (size_t)m * Dd + n;
                out[o] = acc[i][j][rr] + bb + addend[o];
            }
        }
}

// ---------------- sliding-window attention: one wave per output row ----------------
// Padded K/V: key j for row l is padded row (l+j), j=0..31 — branch-free.
// Uniform lanes: D=768 = 64 lanes x 12 elems (3 chunks of 4 at +256-elem stride).
// XCD-chunked block swizzle so each XCD's L2 holds its 512-row K/V slice.
__global__ __launch_bounds__(256) void attn_kernel(
        const bf16* __restrict__ q, const bf16* __restrict__ kp, const bf16* __restrict__ vp,
        bf16* __restrict__ merged) {
    const int wave = threadIdx.x >> 6, lane = threadIdx.x & 63;
    const int bid = blockIdx.x;                      // 1024 blocks
    const int swz = (bid & 7) * 128 + (bid >> 3);    // bijective (1024 = 8*128)
    const int r = swz * 4 + wave;
    const int b = r >> 11, l = r & 2047;
    const bf16* kb = kp + ((size_t)b * LP + l) * Dd;
    const bf16* vb = vp + ((size_t)b * LP + l) * Dd;
    const int eoff = lane * 4;
    const float scale = 0.03608439182435161f;       // 1/sqrt(768)

    float qf[12];
    const bf16* qrow = q + (size_t)r * Dd;
#pragma unroll
    for (int c = 0; c < 3; ++c) {
        short4s t = *reinterpret_cast<const short4s*>(qrow + c * 256 + eoff);
#pragma unroll
        for (int i = 0; i < 4; ++i) qf[c * 4 + i] = b2f(t[i]);
    }

    float s[32];
#pragma unroll
    for (int j = 0; j < 32; ++j) {
        const bf16* kr = kb + (size_t)j * Dd;
        float p = 0.f;
#pragma unroll
        for (int c = 0; c < 3; ++c) {
            short4s t = *reinterpret_cast<const short4s*>(kr + c * 256 + eoff);
#pragma unroll
            for (int i = 0; i < 4; ++i) p += qf[c * 4 + i] * b2f(t[i]);
        }
#pragma unroll
        for (int off = 32; off; off >>= 1) p += __shfl_xor(p, off);
        s[j] = p * scale;
    }

    // softmax(32) and softmax(last 8) share exponentials (shift-invariance)
    float m32 = s[0];
#pragma unroll
    for (int j = 1; j < 32; ++j) m32 = fmaxf(m32, s[j]);
    float sum32 = 0.f;
#pragma unroll
    for (int j = 0; j < 32; ++j) { s[j] = __expf(s[j] - m32); sum32 += s[j]; }
    float sum8 = 0.f;
#pragma unroll
    for (int j = 24; j < 32; ++j) sum8 += s[j];
    float i32 = 0.5f / sum32, i8 = 0.5f / sum8;
#pragma unroll
    for (int j = 0; j < 32; ++j) s[j] = s[j] * i32 + ((j >= 24) ? s[j] * i8 : 0.f);

    // PV
    float acc[12] = {};
#pragma unroll
    for (int j = 0; j < 32; ++j) {
        const bf16* vr = vb + (size_t)j * Dd;
#pragma unroll
        for (int c = 0; c < 3; ++c) {
            short4s t = *reinterpret_cast<const short4s*>(vr + c * 256 + eoff);
#pragma unroll
            for (int i = 0; i < 4; ++i) acc[c * 4 + i] += s[j] * b2f(t[i]);
        }
    }

    bf16* mrow = merged + (size_t)r * Dd;
#pragma unroll
    for (int c = 0; c < 3; ++c) {
        short4s o;
#pragma unroll
        for (int i = 0; i < 4; ++i) o[i] = f2bs(acc[c * 4 + i]);
        *reinterpret_cast<short4s*>(mrow + c * 256 + eoff) = o;
    }
}

extern "C" void kernel_launch(void* const* d_in, const int* in_sizes, int n_in,
                              void* d_out, int out_size, void* d_ws, size_t ws_size,
                              hipStream_t stream) {
    const float* hidden = (const float*)d_in[0];
    const float* sal    = (const float*)d_in[1];
    const float* gw1    = (const float*)d_in[2];
    const float* gb1    = (const float*)d_in[3];
    const float* gw2    = (const float*)d_in[4];
    const float* gb2    = (const float*)d_in[5];
    const float* wq     = (const float*)d_in[6];
    const float* bq     = (const float*)d_in[7];
    const float* wk     = (const float*)d_in[8];
    const float* bk     = (const float*)d_in[9];
    const float* wv     = (const float*)d_in[10];
    const float* bv     = (const float*)d_in[11];
    const float* wo     = (const float*)d_in[12];
    const float* bo     = (const float*)d_in[13];
    float* out = (float*)d_out;

    const size_t nBL  = (size_t)BL * Dd;
    const size_t nPad = (size_t)Bb * LP * Dd;
    char* p = (char*)d_ws;
    bf16* h_b = (bf16*)p; p += nBL * 2;
    bf16* q_b = (bf16*)p; p += nBL * 2;
    bf16* kpd = (bf16*)p; p += nPad * 2;
    bf16* vpd = (bf16*)p; p += nPad * 2;
    bf16* m_b = (bf16*)p; p += nBL * 2;
    bf16* w_b = (bf16*)p; p += (size_t)4 * Dd * Dd * 2;
    size_t used = (size_t)(p - (char*)d_ws);
    float* h_f = (ws_size >= used + nBL * 4) ? (float*)p : out;  // alias-safe in gemm_out

    prep_kernel<<<dim3(CONV_BLOCKS + Bb * 31), 256, 0, stream>>>(wq, wk, wv, wo, bk, bv, w_b, kpd, vpd);
    gate_kernel<<<dim3(BL), 256, 0, stream>>>(hidden, sal, gw1, gb1, gw2, gb2, h_f, h_b);
    gemm_qkv<<<dim3(576), 256, 0, stream>>>(h_b, w_b, bq, bk, bv, q_b, kpd, vpd);
    attn_kernel<<<dim3(BL / 4), 256, 0, stream>>>(q_b, kpd, vpd, m_b);
    gemm_out<<<dim3(384), 256, 0, stream>>>(m_b, w_b + (size_t)3 * Dd * Dd, bo, h_f, out);
}

// Round 4
// 95.549 us; speedup vs baseline: 2.7698x; 1.4691x over previous
//
#include <hip/hip_runtime.h>
#include <hip/hip_bf16.h>
#include <stdint.h>

#define Bb 2
#define Ll 2048
#define Dd 768
#define HID 32
#define BL (Bb*Ll)     // 4096
#define LP (Ll+31)     // padded K/V rows per batch

typedef __hip_bfloat16 bf16;
typedef __attribute__((ext_vector_type(8))) short short8;
typedef __attribute__((ext_vector_type(4))) short short4s;
typedef __attribute__((ext_vector_type(4))) float floatx4;

__device__ __forceinline__ float b2f(short u) {
    union { float f; unsigned i; } x; x.i = ((unsigned)(unsigned short)u) << 16; return x.f;
}
__device__ __forceinline__ bf16 f2b(float x) { return __float2bfloat16(x); }
__device__ __forceinline__ short f2bs(float x) {
    bf16 t = __float2bfloat16(x);
    union { bf16 h; short s; } u; u.h = t; return u.s;
}

typedef __attribute__((address_space(1))) const unsigned int guint;
typedef __attribute__((address_space(3))) unsigned int luint;
__device__ __forceinline__ void gload16(const bf16* g, bf16* l) {
    __builtin_amdgcn_global_load_lds((guint*)g, (luint*)l, 16, 0, 0);
}

// ---------------- prep: weight convert + K/V pad fill + gw2 transpose ----------------
#define CONV_BLOCKS 2304   // 4*768*768/4 float4 / 256
#define PAD_BLOCKS  (Bb*31)
#define TR_BLOCKS   96     // 32*768/256
__global__ void prep_kernel(const float* __restrict__ wq, const float* __restrict__ wk,
                            const float* __restrict__ wv, const float* __restrict__ wo,
                            const float* __restrict__ bk, const float* __restrict__ bv,
                            const float* __restrict__ gw2,
                            bf16* __restrict__ wout, bf16* __restrict__ kp, bf16* __restrict__ vp,
                            float* __restrict__ gw2T) {
    if (blockIdx.x < CONV_BLOCKS) {
        int idx = blockIdx.x * 256 + threadIdx.x;
        const int per = Dd * Dd / 4;
        int w = idx / per, r = idx % per;
        const float* src = (w == 0) ? wq : (w == 1) ? wk : (w == 2) ? wv : wo;
        float4 v = reinterpret_cast<const float4*>(src)[r];
        bf16* o = wout + (size_t)w * Dd * Dd + (size_t)r * 4;
        o[0] = f2b(v.x); o[1] = f2b(v.y); o[2] = f2b(v.z); o[3] = f2b(v.w);
    } else if (blockIdx.x < CONV_BLOCKS + PAD_BLOCKS) {
        int pb = blockIdx.x - CONV_BLOCKS;        // 0..61
        int b = pb / 31, row = pb % 31;
        size_t base = ((size_t)b * LP + row) * Dd;
        for (int i = threadIdx.x; i < Dd; i += 256) {
            kp[base + i] = f2b(bk[i]);
            vp[base + i] = f2b(bv[i]);
        }
    } else {
        // gw2T[j][d] = gw2[d][j]; coalesced writes, L1/L2-hit scattered reads
        int o = (blockIdx.x - CONV_BLOCKS - PAD_BLOCKS) * 256 + threadIdx.x;  // [0, 24576)
        int j = o / Dd, d = o - j * Dd;
        gw2T[o] = gw2[d * HID + j];
    }
}

// ---------------- gate MLP + h = hidden * gate (coalesced gw2T, 8 rows/block) ----------------
__global__ __launch_bounds__(256) void gate_kernel(
        const float* __restrict__ hidden, const float* __restrict__ sal,
        const float* __restrict__ gw1, const float* __restrict__ gb1,
        const float* __restrict__ gw2T, const float* __restrict__ gb2,
        float* __restrict__ h_f, bf16* __restrict__ h_b) {
    __shared__ float h1s[8][HID];
    int row0 = blockIdx.x * 8;
    int t = threadIdx.x;
    {   // 8 rows x 32 = 256 h1 values, one per thread
        int rr = t >> 5, j = t & 31;
        float s = sal[row0 + rr];
        float x = s * gw1[j] + gb1[j];
        h1s[rr][j] = x / (1.f + __expf(-x));   // silu
    }
    __syncthreads();
#pragma unroll
    for (int dl = 0; dl < 3; ++dl) {
        int d = t + dl * 256;
        float base = gb2[d];
        float acc[8];
#pragma unroll
        for (int rr = 0; rr < 8; ++rr) acc[rr] = base;
#pragma unroll
        for (int j = 0; j < HID; ++j) {
            float wj = gw2T[j * Dd + d];           // coalesced, L2-resident
#pragma unroll
            for (int rr = 0; rr < 8; ++rr) acc[rr] += h1s[rr][j] * wj;  // LDS broadcast
        }
#pragma unroll
        for (int rr = 0; rr < 8; ++rr) {
            float g = 1.f / (1.f + __expf(-acc[rr]));
            g = fminf(fmaxf(g, 0.05f), 0.95f);
            size_t off = (size_t)(row0 + rr) * Dd + d;
            float hv = hidden[off] * g;
            h_f[off] = hv;
            h_b[off] = f2b(hv);
        }
    }
}

// ---------------- shared MFMA GEMM core: C = A(M x 768) * W(N x 768)^T ----------------
// m97 structure: 128 x (NF*32) tile, BK=64, global_load_lds width 16 with
// pre-swizzled global source (linear LDS dest), XOR-swizzled ds_read_b128.
template<int NF>   // wave n-frags: 4 -> BN=128, 2 -> BN=64
__device__ __forceinline__ void gemm_core(const bf16* __restrict__ Ag, const bf16* __restrict__ Wg,
                                          int m0, int n0, bf16* As, bf16* Bs,
                                          floatx4 (&acc)[4][NF]) {
    const int tid  = threadIdx.x;
    const int wave = tid >> 6, lane = tid & 63;
    const int lrow = lane & 15, koff = (lane >> 4) * 8;
    const int wm = (wave >> 1) * 64, wn = (wave & 1) * (NF * 16);
    const char* Asb = (const char*)As;
    const char* Bsb = (const char*)Bs;

    for (int k0 = 0; k0 < Dd; k0 += 64) {
        // stage A: 128x64 bf16 = 16KB, linear LDS, inverse-swizzled source
#pragma unroll
        for (int c = 0; c < 4; ++c) {
            int p = tid * 16 + c * 4096;              // linear LDS byte this lane fills
            int r = p >> 7;                           // row (128B rows)
            int o = (p & 127) ^ ((r & 7) << 4);       // swizzled source byte-in-row
            gload16(Ag + (size_t)(m0 + r) * Dd + k0 + (o >> 1),
                    As + (wave * 1024 + c * 4096) / 2);   // wave-uniform base
        }
        // stage B: NF*32 x 64 bf16
#pragma unroll
        for (int c = 0; c < NF; ++c) {
            int p = tid * 16 + c * 4096;
            int r = p >> 7;
            int o = (p & 127) ^ ((r & 7) << 4);
            gload16(Wg + (size_t)(n0 + r) * Dd + k0 + (o >> 1),
                    Bs + (wave * 1024 + c * 4096) / 2);
        }
        __syncthreads();   // includes vmcnt(0) drain of global_load_lds
#pragma unroll
        for (int kk = 0; kk < 64; kk += 32) {
            short8 a[4], b[NF];
#pragma unroll
            for (int i = 0; i < 4; ++i) {
                int row = wm + i * 16 + lrow;
                int byt = (row << 7) + (((kk + koff) * 2) ^ ((row & 7) << 4));
                a[i] = *reinterpret_cast<const short8*>(Asb + byt);
            }
#pragma unroll
            for (int j = 0; j < NF; ++j) {
                int row = wn + j * 16 + lrow;
                int byt = (row << 7) + (((kk + koff) * 2) ^ ((row & 7) << 4));
                b[j] = *reinterpret_cast<const short8*>(Bsb + byt);
            }
#pragma unroll
            for (int i = 0; i < 4; ++i)
#pragma unroll
                for (int j = 0; j < NF; ++j)
                    acc[i][j] = __builtin_amdgcn_mfma_f32_16x16x32_bf16(a[i], b[j], acc[i][j], 0, 0, 0);
        }
        __syncthreads();
    }
}

// ---------------- fused QKV GEMM, k/v written into padded arrays ----------------
// 1D grid 576, XCD-chunked 2D swizzle: 8 XCDs as 4(m) x 2(n) chunks of 8 mtiles x 9 ntiles.
__global__ __launch_bounds__(256) void gemm_qkv(
        const bf16* __restrict__ A, const bf16* __restrict__ W3,
        const float* __restrict__ bq, const float* __restrict__ bk, const float* __restrict__ bv,
        bf16* __restrict__ qo, bf16* __restrict__ kp, bf16* __restrict__ vp) {
    __shared__ bf16 As[128 * 64];
    __shared__ bf16 Bs[128 * 64];
    int bid = blockIdx.x;
    int xcd = bid & 7, idx = bid >> 3;       // idx in [0,72)
    int mtile = (xcd >> 1) * 8 + (idx & 7);  // [0,32)
    int ntile = (xcd & 1) * 9 + (idx >> 3);  // [0,18)
    int tgt = ntile / 6;
    int n0 = (ntile % 6) * 128;
    int m0 = mtile * 128;
    const bf16* W = W3 + (size_t)tgt * Dd * Dd;
    const float* bias = (tgt == 0) ? bq : (tgt == 1) ? bk : bv;
    bf16* out = (tgt == 0) ? qo : (tgt == 1) ? kp : vp;

    floatx4 acc[4][4] = {};
    gemm_core<4>(A, W, m0, n0, As, Bs, acc);

    int wave = threadIdx.x >> 6, lane = threadIdx.x & 63;
    int wm = (wave >> 1) * 64, wn = (wave & 1) * 64;
    int crow = (lane >> 4) * 4, ccol = lane & 15;
#pragma unroll
    for (int i = 0; i < 4; ++i)
#pragma unroll
        for (int j = 0; j < 4; ++j) {
            int n = n0 + wn + j * 16 + ccol;
            float bb = bias[n];
#pragma unroll
            for (int rr = 0; rr < 4; ++rr) {
                int m = m0 + wm + i * 16 + crow + rr;
                size_t orow = (tgt == 0) ? (size_t)m
                                         : ((size_t)(m >> 11) * LP + 31 + (m & 2047));
                out[orow * Dd + n] = f2b(acc[i][j][rr] + bb);
            }
        }
}

// ---------------- output GEMM: out = merged @ wo^T + bo + h (fp32) ----------------
// 1D grid 384, XCD-chunked: 4(m) x 2(n) chunks of 8 mtiles x 6 ntiles.
__global__ __launch_bounds__(256) void gemm_out(
        const bf16* __restrict__ A, const bf16* __restrict__ W,
        const float* __restrict__ bias, const float* __restrict__ addend,
        float* __restrict__ out) {
    __shared__ bf16 As[128 * 64];
    __shared__ bf16 Bs[64 * 64];
    int bid = blockIdx.x;
    int xcd = bid & 7, idx = bid >> 3;       // idx in [0,48)
    int mtile = (xcd >> 1) * 8 + (idx & 7);  // [0,32)
    int ntile = (xcd & 1) * 6 + (idx >> 3);  // [0,12)
    int n0 = ntile * 64, m0 = mtile * 128;

    floatx4 acc[4][2] = {};
    gemm_core<2>(A, W, m0, n0, As, Bs, acc);

    int wave = threadIdx.x >> 6, lane = threadIdx.x & 63;
    int wm = (wave >> 1) * 64, wn = (wave & 1) * 32;
    int crow = (lane >> 4) * 4, ccol = lane & 15;
#pragma unroll
    for (int i = 0; i < 4; ++i)
#pragma unroll
        for (int j = 0; j < 2; ++j) {
            int n = n0 + wn + j * 16 + ccol;
            float bb = bias[n];
#pragma unroll
            for (int rr = 0; rr < 4; ++rr) {
                int m = m0 + wm + i * 16 + crow + rr;
                size_t o = (size_t)m * Dd + n;
                out[o] = acc[i][j][rr] + bb + addend[o];
            }
        }
}

// ---------------- sliding-window attention: one wave per output row ----------------
// Padded K/V: key j for row l is padded row (l+j), j=0..31 — branch-free.
// Uniform lanes: D=768 = 64 lanes x 12 elems (3 chunks of 4 at +256-elem stride).
// XCD-chunked block swizzle so each XCD's L2 holds its 512-row K/V slice.
__global__ __launch_bounds__(256) void attn_kernel(
        const bf16* __restrict__ q, const bf16* __restrict__ kp, const bf16* __restrict__ vp,
        bf16* __restrict__ merged) {
    const int wave = threadIdx.x >> 6, lane = threadIdx.x & 63;
    const int bid = blockIdx.x;                      // 1024 blocks
    const int swz = (bid & 7) * 128 + (bid >> 3);    // bijective (1024 = 8*128)
    const int r = swz * 4 + wave;
    const int b = r >> 11, l = r & 2047;
    const bf16* kb = kp + ((size_t)b * LP + l) * Dd;
    const bf16* vb = vp + ((size_t)b * LP + l) * Dd;
    const int eoff = lane * 4;
    const float scale = 0.03608439182435161f;       // 1/sqrt(768)

    float qf[12];
    const bf16* qrow = q + (size_t)r * Dd;
#pragma unroll
    for (int c = 0; c < 3; ++c) {
        short4s t = *reinterpret_cast<const short4s*>(qrow + c * 256 + eoff);
#pragma unroll
        for (int i = 0; i < 4; ++i) qf[c * 4 + i] = b2f(t[i]);
    }

    float s[32];
#pragma unroll
    for (int j = 0; j < 32; ++j) {
        const bf16* kr = kb + (size_t)j * Dd;
        float p = 0.f;
#pragma unroll
        for (int c = 0; c < 3; ++c) {
            short4s t = *reinterpret_cast<const short4s*>(kr + c * 256 + eoff);
#pragma unroll
            for (int i = 0; i < 4; ++i) p += qf[c * 4 + i] * b2f(t[i]);
        }
#pragma unroll
        for (int off = 32; off; off >>= 1) p += __shfl_xor(p, off);
        s[j] = p * scale;
    }

    // softmax(32) and softmax(last 8) share exponentials (shift-invariance)
    float m32 = s[0];
#pragma unroll
    for (int j = 1; j < 32; ++j) m32 = fmaxf(m32, s[j]);
    float sum32 = 0.f;
#pragma unroll
    for (int j = 0; j < 32; ++j) { s[j] = __expf(s[j] - m32); sum32 += s[j]; }
    float sum8 = 0.f;
#pragma unroll
    for (int j = 24; j < 32; ++j) sum8 += s[j];
    float i32 = 0.5f / sum32, i8 = 0.5f / sum8;
#pragma unroll
    for (int j = 0; j < 32; ++j) s[j] = s[j] * i32 + ((j >= 24) ? s[j] * i8 : 0.f);

    // PV
    float acc[12] = {};
#pragma unroll
    for (int j = 0; j < 32; ++j) {
        const bf16* vr = vb + (size_t)j * Dd;
#pragma unroll
        for (int c = 0; c < 3; ++c) {
            short4s t = *reinterpret_cast<const short4s*>(vr + c * 256 + eoff);
#pragma unroll
            for (int i = 0; i < 4; ++i) acc[c * 4 + i] += s[j] * b2f(t[i]);
        }
    }

    bf16* mrow = merged + (size_t)r * Dd;
#pragma unroll
    for (int c = 0; c < 3; ++c) {
        short4s o;
#pragma unroll
        for (int i = 0; i < 4; ++i) o[i] = f2bs(acc[c * 4 + i]);
        *reinterpret_cast<short4s*>(mrow + c * 256 + eoff) = o;
    }
}

extern "C" void kernel_launch(void* const* d_in, const int* in_sizes, int n_in,
                              void* d_out, int out_size, void* d_ws, size_t ws_size,
                              hipStream_t stream) {
    const float* hidden = (const float*)d_in[0];
    const float* sal    = (const float*)d_in[1];
    const float* gw1    = (const float*)d_in[2];
    const float* gb1    = (const float*)d_in[3];
    const float* gw2    = (const float*)d_in[4];
    const float* gb2    = (const float*)d_in[5];
    const float* wq     = (const float*)d_in[6];
    const float* bq     = (const float*)d_in[7];
    const float* wk     = (const float*)d_in[8];
    const float* bk     = (const float*)d_in[9];
    const float* wv     = (const float*)d_in[10];
    const float* bv     = (const float*)d_in[11];
    const float* wo     = (const float*)d_in[12];
    const float* bo     = (const float*)d_in[13];
    float* out = (float*)d_out;

    const size_t nBL  = (size_t)BL * Dd;
    const size_t nPad = (size_t)Bb * LP * Dd;
    char* p = (char*)d_ws;
    bf16* h_b = (bf16*)p; p += nBL * 2;
    bf16* q_b = (bf16*)p; p += nBL * 2;
    bf16* kpd = (bf16*)p; p += nPad * 2;
    bf16* vpd = (bf16*)p; p += nPad * 2;
    bf16* m_b = (bf16*)p; p += nBL * 2;
    bf16* w_b = (bf16*)p; p += (size_t)4 * Dd * Dd * 2;
    float* g2T = (float*)p; p += (size_t)HID * Dd * 4;
    size_t used = (size_t)(p - (char*)d_ws);
    float* h_f = (ws_size >= used + nBL * 4) ? (float*)p : out;  // alias-safe in gemm_out

    prep_kernel<<<dim3(CONV_BLOCKS + PAD_BLOCKS + TR_BLOCKS), 256, 0, stream>>>(
        wq, wk, wv, wo, bk, bv, gw2, w_b, kpd, vpd, g2T);
    gate_kernel<<<dim3(BL / 8), 256, 0, stream>>>(hidden, sal, gw1, gb1, g2T, gb2, h_f, h_b);
    gemm_qkv<<<dim3(576), 256, 0, stream>>>(h_b, w_b, bq, bk, bv, q_b, kpd, vpd);
    attn_kernel<<<dim3(BL / 4), 256, 0, stream>>>(q_b, kpd, vpd, m_b);
    gemm_out<<<dim3(384), 256, 0, stream>>>(m_b, w_b + (size_t)3 * Dd * Dd, bo, h_f, out);
}

// Round 5
// 84.260 us; speedup vs baseline: 3.1409x; 1.1340x over previous
//
#include <hip/hip_runtime.h>
#include <hip/hip_bf16.h>
#include <stdint.h>

#define Bb 2
#define Ll 2048
#define Dd 768
#define HID 32
#define BL (Bb*Ll)        // 4096
#define KPAD 32           // leading pad rows/cols (>=32 for aligned 64-key panels)
#define KROWS (KPAD+Ll+16)  // 2096 = padded K rows / vT cols per batch

typedef __hip_bfloat16 bf16;
typedef __attribute__((ext_vector_type(8))) short short8;
typedef __attribute__((ext_vector_type(4))) short short4s;
typedef __attribute__((ext_vector_type(4))) float floatx4;

__device__ __forceinline__ float b2f(short u) {
    union { float f; unsigned i; } x; x.i = ((unsigned)(unsigned short)u) << 16; return x.f;
}
__device__ __forceinline__ bf16 f2b(float x) { return __float2bfloat16(x); }
__device__ __forceinline__ short f2bs(float x) {
    bf16 t = __float2bfloat16(x);
    union { bf16 h; short s; } u; u.h = t; return u.s;
}

typedef __attribute__((address_space(1))) const unsigned int guint;
typedef __attribute__((address_space(3))) unsigned int luint;
__device__ __forceinline__ void gload16(const bf16* g, bf16* l) {
    __builtin_amdgcn_global_load_lds((guint*)g, (luint*)l, 16, 0, 0);
}

// ---------------- prep: weight convert + K pad + vT pad + gw2 transpose ----------------
#define CONV_BLOCKS 2304                    // 4*768*768/4 float4 / 256
#define KP_BLOCKS   (Bb*48)                 // 96: 32 lead + 16 trail rows per batch
#define VT_BLOCKS   ((Bb*Dd*48)/256)        // 288: 32 lead + 16 trail cols per (b,n)
#define TR_BLOCKS   96                      // 32*768/256
__global__ void prep_kernel(const float* __restrict__ wq, const float* __restrict__ wk,
                            const float* __restrict__ wv, const float* __restrict__ wo,
                            const float* __restrict__ bk, const float* __restrict__ bv,
                            const float* __restrict__ gw2,
                            bf16* __restrict__ wout, bf16* __restrict__ kp, bf16* __restrict__ vT,
                            float* __restrict__ gw2T) {
    int bx = blockIdx.x;
    if (bx < CONV_BLOCKS) {
        int idx = bx * 256 + threadIdx.x;
        const int per = Dd * Dd / 4;
        int w = idx / per, r = idx % per;
        const float* src = (w == 0) ? wq : (w == 1) ? wk : (w == 2) ? wv : wo;
        float4 v = reinterpret_cast<const float4*>(src)[r];
        bf16* o = wout + (size_t)w * Dd * Dd + (size_t)r * 4;
        o[0] = f2b(v.x); o[1] = f2b(v.y); o[2] = f2b(v.z); o[3] = f2b(v.w);
    } else if (bx < CONV_BLOCKS + KP_BLOCKS) {
        int pb = bx - CONV_BLOCKS;            // 0..95
        int b = pb / 48, c = pb % 48;
        int row = (c < 32) ? c : (KPAD + Ll + (c - 32));
        size_t base = ((size_t)b * KROWS + row) * Dd;
        for (int i = threadIdx.x; i < Dd; i += 256)
            kp[base + i] = (c < 32) ? f2b(bk[i]) : f2b(0.f);
    } else if (bx < CONV_BLOCKS + KP_BLOCKS + VT_BLOCKS) {
        int o = (bx - CONV_BLOCKS - KP_BLOCKS) * 256 + threadIdx.x;   // [0, 2*768*48)
        int b = o / (Dd * 48); int rem = o - b * Dd * 48;
        int n = rem / 48, c = rem % 48;
        int col = (c < 32) ? c : (KPAD + Ll + (c - 32));
        vT[((size_t)b * Dd + n) * KROWS + col] = (c < 32) ? f2b(bv[n]) : f2b(0.f);
    } else {
        int o = (bx - CONV_BLOCKS - KP_BLOCKS - VT_BLOCKS) * 256 + threadIdx.x;
        int j = o / Dd, d = o - j * Dd;
        gw2T[o] = gw2[d * HID + j];
    }
}

// ---------------- gate MLP + h = hidden * gate (bf16 h only) ----------------
__global__ __launch_bounds__(256) void gate_kernel(
        const float* __restrict__ hidden, const float* __restrict__ sal,
        const float* __restrict__ gw1, const float* __restrict__ gb1,
        const float* __restrict__ gw2T, const float* __restrict__ gb2,
        bf16* __restrict__ h_b) {
    __shared__ float h1s[8][HID];
    int row0 = blockIdx.x * 8;
    int t = threadIdx.x;
    {
        int rr = t >> 5, j = t & 31;
        float s = sal[row0 + rr];
        float x = s * gw1[j] + gb1[j];
        h1s[rr][j] = x / (1.f + __expf(-x));   // silu
    }
    __syncthreads();
#pragma unroll
    for (int dl = 0; dl < 3; ++dl) {
        int d = t + dl * 256;
        float base = gb2[d];
        float acc[8];
#pragma unroll
        for (int rr = 0; rr < 8; ++rr) acc[rr] = base;
#pragma unroll
        for (int j = 0; j < HID; ++j) {
            float wj = gw2T[j * Dd + d];
#pragma unroll
            for (int rr = 0; rr < 8; ++rr) acc[rr] += h1s[rr][j] * wj;
        }
#pragma unroll
        for (int rr = 0; rr < 8; ++rr) {
            float g = 1.f / (1.f + __expf(-acc[rr]));
            g = fminf(fmaxf(g, 0.05f), 0.95f);
            size_t off = (size_t)(row0 + rr) * Dd + d;
            h_b[off] = f2b(hidden[off] * g);
        }
    }
}

// ---------------- shared MFMA GEMM core (m97 structure) ----------------
template<int NF>
__device__ __forceinline__ void gemm_core(const bf16* __restrict__ Ag, const bf16* __restrict__ Wg,
                                          int m0, int n0, bf16* As, bf16* Bs,
                                          floatx4 (&acc)[4][NF]) {
    const int tid  = threadIdx.x;
    const int wave = tid >> 6, lane = tid & 63;
    const int lrow = lane & 15, koff = (lane >> 4) * 8;
    const int wm = (wave >> 1) * 64, wn = (wave & 1) * (NF * 16);
    const char* Asb = (const char*)As;
    const char* Bsb = (const char*)Bs;

    for (int k0 = 0; k0 < Dd; k0 += 64) {
#pragma unroll
        for (int c = 0; c < 4; ++c) {
            int p = tid * 16 + c * 4096;
            int r = p >> 7;
            int o = (p & 127) ^ ((r & 7) << 4);
            gload16(Ag + (size_t)(m0 + r) * Dd + k0 + (o >> 1),
                    As + (wave * 1024 + c * 4096) / 2);
        }
#pragma unroll
        for (int c = 0; c < NF; ++c) {
            int p = tid * 16 + c * 4096;
            int r = p >> 7;
            int o = (p & 127) ^ ((r & 7) << 4);
            gload16(Wg + (size_t)(n0 + r) * Dd + k0 + (o >> 1),
                    Bs + (wave * 1024 + c * 4096) / 2);
        }
        __syncthreads();
#pragma unroll
        for (int kk = 0; kk < 64; kk += 32) {
            short8 a[4], b[NF];
#pragma unroll
            for (int i = 0; i < 4; ++i) {
                int row = wm + i * 16 + lrow;
                int byt = (row << 7) + (((kk + koff) * 2) ^ ((row & 7) << 4));
                a[i] = *reinterpret_cast<const short8*>(Asb + byt);
            }
#pragma unroll
            for (int j = 0; j < NF; ++j) {
                int row = wn + j * 16 + lrow;
                int byt = (row << 7) + (((kk + koff) * 2) ^ ((row & 7) << 4));
                b[j] = *reinterpret_cast<const short8*>(Bsb + byt);
            }
#pragma unroll
            for (int i = 0; i < 4; ++i)
#pragma unroll
                for (int j = 0; j < NF; ++j)
                    acc[i][j] = __builtin_amdgcn_mfma_f32_16x16x32_bf16(a[i], b[j], acc[i][j], 0, 0, 0);
        }
        __syncthreads();
    }
}

// ---------------- fused QKV GEMM: q rows, k into padded kpd, v into TRANSPOSED vT ----------------
__global__ __launch_bounds__(256) void gemm_qkv(
        const bf16* __restrict__ A, const bf16* __restrict__ W3,
        const float* __restrict__ bq, const float* __restrict__ bk, const float* __restrict__ bv,
        bf16* __restrict__ qo, bf16* __restrict__ kp, bf16* __restrict__ vT) {
    __shared__ bf16 As[128 * 64];
    __shared__ bf16 Bs[128 * 64];
    int bid = blockIdx.x;
    int xcd = bid & 7, idx = bid >> 3;
    int mtile = (xcd >> 1) * 8 + (idx & 7);
    int ntile = (xcd & 1) * 9 + (idx >> 3);
    int tgt = ntile / 6;
    int n0 = (ntile % 6) * 128;
    int m0 = mtile * 128;
    const bf16* W = W3 + (size_t)tgt * Dd * Dd;
    const float* bias = (tgt == 0) ? bq : (tgt == 1) ? bk : bv;

    floatx4 acc[4][4] = {};
    gemm_core<4>(A, W, m0, n0, As, Bs, acc);

    int wave = threadIdx.x >> 6, lane = threadIdx.x & 63;
    int wm = (wave >> 1) * 64, wn = (wave & 1) * 64;
    int crow = (lane >> 4) * 4, ccol = lane & 15;
#pragma unroll
    for (int i = 0; i < 4; ++i)
#pragma unroll
        for (int j = 0; j < 4; ++j) {
            int n = n0 + wn + j * 16 + ccol;
            float bb = bias[n];
            int m = m0 + wm + i * 16 + crow;
            int b_ = m >> 11, l = m & 2047;
            if (tgt == 2) {
                short4s pk;
#pragma unroll
                for (int rr = 0; rr < 4; ++rr) pk[rr] = f2bs(acc[i][j][rr] + bb);
                *reinterpret_cast<short4s*>(vT + ((size_t)b_ * Dd + n) * KROWS + KPAD + l) = pk;
            } else {
#pragma unroll
                for (int rr = 0; rr < 4; ++rr) {
                    size_t orow = (tgt == 0) ? (size_t)(m + rr)
                                             : ((size_t)b_ * KROWS + KPAD + l + rr);
                    bf16* out = (tgt == 0) ? qo : kp;
                    out[orow * Dd + n] = f2b(acc[i][j][rr] + bb);
                }
            }
        }
}

// ---------------- output GEMM: out = merged @ wo^T + bo + h (bf16 addend, fp32 out) ----------------
__global__ __launch_bounds__(256) void gemm_out(
        const bf16* __restrict__ A, const bf16* __restrict__ W,
        const float* __restrict__ bias, const bf16* __restrict__ addend,
        float* __restrict__ out) {
    __shared__ bf16 As[128 * 64];
    __shared__ bf16 Bs[64 * 64];
    int bid = blockIdx.x;
    int xcd = bid & 7, idx = bid >> 3;
    int mtile = (xcd >> 1) * 8 + (idx & 7);
    int ntile = (xcd & 1) * 6 + (idx >> 3);
    int n0 = ntile * 64, m0 = mtile * 128;

    floatx4 acc[4][2] = {};
    gemm_core<2>(A, W, m0, n0, As, Bs, acc);

    int wave = threadIdx.x >> 6, lane = threadIdx.x & 63;
    int wm = (wave >> 1) * 64, wn = (wave & 1) * 32;
    int crow = (lane >> 4) * 4, ccol = lane & 15;
#pragma unroll
    for (int i = 0; i < 4; ++i)
#pragma unroll
        for (int j = 0; j < 2; ++j) {
            int n = n0 + wn + j * 16 + ccol;
            float bb = bias[n];
#pragma unroll
            for (int rr = 0; rr < 4; ++rr) {
                int m = m0 + wm + i * 16 + crow + rr;
                size_t o = (size_t)m * Dd + n;
                out[o] = acc[i][j][rr] + bb + b2f(*(const short*)(addend + o));
            }
        }
}

// ---------------- MFMA banded sliding-window attention ----------------
// One wave (64-thr block) per 16 query rows. 256 blocks.
// S(16x64) = Q(16x768) x Kpanel(64x768)^T via mfma, Q/K read direct from global.
// Banded softmax in-register (valid j in [r+1, r+32]; w8 sub-band [r+25, r+32]).
// W~ bounced through 2KB XOR-swizzled LDS; PV = mfma(vT_frag, W~_frag) -> 8B stores.
__global__ __launch_bounds__(64) void attn_kernel(
        const bf16* __restrict__ q, const bf16* __restrict__ kp, const bf16* __restrict__ vT,
        bf16* __restrict__ merged) {
    __shared__ bf16 wlds[16 * 64];
    const int lane = threadIdx.x;
    const int bid = blockIdx.x;                    // 256
    const int g = (bid & 7) * 32 + (bid >> 3);     // XCD-chunked, bijective (256=8*32)
    const int b = g >> 7, L0 = (g & 127) * 16;
    const int lrow = lane & 15, koff = (lane >> 4) * 8;
    const int crow = (lane >> 4) * 4, ccol = lane & 15;
    const float scale = 0.03608439182435161f;      // 1/sqrt(768)

    // ---- QK^T: S[q][j], panel keys j=0..63 <-> kpd rows L0+j (actual keys L0-32+j)
    const bf16* qbase = q  + ((size_t)(b * Ll + L0 + lrow)) * Dd + koff;
    const bf16* kbase = kp + ((size_t)b * KROWS + L0 + lrow) * Dd + koff;
    floatx4 s[4] = {};
    for (int ks = 0; ks < 24; ++ks) {
        short8 a = *reinterpret_cast<const short8*>(qbase + ks * 32);
#pragma unroll
        for (int f = 0; f < 4; ++f) {
            short8 bb = *reinterpret_cast<const short8*>(kbase + (size_t)f * 16 * Dd + ks * 32);
            s[f] = __builtin_amdgcn_mfma_f32_16x16x32_bf16(a, bb, s[f], 0, 0, 0);
        }
    }

    // ---- banded softmax, rows r = crow+rr; lane holds col j = f*16+ccol
#pragma unroll
    for (int rr = 0; rr < 4; ++rr) {
        int r = crow + rr;
        float z[4], e[4];
#pragma unroll
        for (int f = 0; f < 4; ++f) {
            int j = f * 16 + ccol;
            bool valid = (j >= r + 1) && (j <= r + 32);
            z[f] = valid ? s[f][rr] * scale : -3.0e38f;
        }
        float m = fmaxf(fmaxf(z[0], z[1]), fmaxf(z[2], z[3]));
#pragma unroll
        for (int off = 1; off < 16; off <<= 1) m = fmaxf(m, __shfl_xor(m, off));
        float S32 = 0.f, S8 = 0.f;
#pragma unroll
        for (int f = 0; f < 4; ++f) {
            e[f] = __expf(z[f] - m);               // invalid -> exp(-huge) = 0
            S32 += e[f];
            int j = f * 16 + ccol;
            S8 += ((j >= r + 25) && (j <= r + 32)) ? e[f] : 0.f;
        }
#pragma unroll
        for (int off = 1; off < 16; off <<= 1) {
            S32 += __shfl_xor(S32, off);
            S8  += __shfl_xor(S8, off);
        }
        float i32 = 0.5f / S32, i8 = 0.5f / S8;
#pragma unroll
        for (int f = 0; f < 4; ++f) {
            int j = f * 16 + ccol;
            float w = e[f] * i32 + (((j >= r + 25) && (j <= r + 32)) ? e[f] * i8 : 0.f);
            int byt = ((r * 64 + j) * 2) ^ ((r & 7) << 4);
            *reinterpret_cast<bf16*>(reinterpret_cast<char*>(wlds) + byt) = f2b(w);
        }
    }
    __syncthreads();   // single wave: orders ds_write -> ds_read

    // ---- PV: O = W~(16x64) x Vpanel; computed as mfma(vT_frag, W~_frag) -> D[n][q]
    short8 wa[2];
#pragma unroll
    for (int ks = 0; ks < 2; ++ks) {
        int byt = ((lrow * 64 + ks * 32 + koff) * 2) ^ ((lrow & 7) << 4);
        wa[ks] = *reinterpret_cast<const short8*>(reinterpret_cast<const char*>(wlds) + byt);
    }
    const bf16* vbase = vT + (size_t)b * Dd * KROWS + L0;
    bf16* obase = merged + ((size_t)(b * Ll + L0 + ccol)) * Dd;
    for (int c = 0; c < 6; ++c) {
#pragma unroll
        for (int fn = 0; fn < 8; ++fn) {
            int nr = c * 128 + fn * 16;
            floatx4 acc = {};
#pragma unroll
            for (int ks = 0; ks < 2; ++ks) {
                short8 bb = *reinterpret_cast<const short8*>(vbase + (size_t)(nr + lrow) * KROWS + ks * 32 + koff);
                acc = __builtin_amdgcn_mfma_f32_16x16x32_bf16(bb, wa[ks], acc, 0, 0, 0);
            }
            short4s pk;
#pragma unroll
            for (int rr = 0; rr < 4; ++rr) pk[rr] = f2bs(acc[rr]);
            *reinterpret_cast<short4s*>(obase + nr + crow) = pk;
        }
    }
}

extern "C" void kernel_launch(void* const* d_in, const int* in_sizes, int n_in,
                              void* d_out, int out_size, void* d_ws, size_t ws_size,
                              hipStream_t stream) {
    const float* hidden = (const float*)d_in[0];
    const float* sal    = (const float*)d_in[1];
    const float* gw1    = (const float*)d_in[2];
    const float* gb1    = (const float*)d_in[3];
    const float* gw2    = (const float*)d_in[4];
    const float* gb2    = (const float*)d_in[5];
    const float* wq     = (const float*)d_in[6];
    const float* bq     = (const float*)d_in[7];
    const float* wk     = (const float*)d_in[8];
    const float* bk     = (const float*)d_in[9];
    const float* wv     = (const float*)d_in[10];
    const float* bv     = (const float*)d_in[11];
    const float* wo     = (const float*)d_in[12];
    const float* bo     = (const float*)d_in[13];
    float* out = (float*)d_out;

    const size_t nBL  = (size_t)BL * Dd;
    const size_t nPad = (size_t)Bb * KROWS * Dd;
    char* p = (char*)d_ws;
    bf16* h_b = (bf16*)p; p += nBL * 2;
    bf16* q_b = (bf16*)p; p += nBL * 2;
    bf16* kpd = (bf16*)p; p += nPad * 2;
    bf16* vT  = (bf16*)p; p += nPad * 2;
    bf16* m_b = (bf16*)p; p += nBL * 2;
    bf16* w_b = (bf16*)p; p += (size_t)4 * Dd * Dd * 2;
    float* g2T = (float*)p; p += (size_t)HID * Dd * 4;

    prep_kernel<<<dim3(CONV_BLOCKS + KP_BLOCKS + VT_BLOCKS + TR_BLOCKS), 256, 0, stream>>>(
        wq, wk, wv, wo, bk, bv, gw2, w_b, kpd, vT, g2T);
    gate_kernel<<<dim3(BL / 8), 256, 0, stream>>>(hidden, sal, gw1, gb1, g2T, gb2, h_b);
    gemm_qkv<<<dim3(576), 256, 0, stream>>>(h_b, w_b, bq, bk, bv, q_b, kpd, vT);
    attn_kernel<<<dim3(256), 64, 0, stream>>>(q_b, kpd, vT, m_b);
    gemm_out<<<dim3(384), 256, 0, stream>>>(m_b, w_b + (size_t)3 * Dd * Dd, bo, h_b, out);
}